// Round 8
// baseline (260.272 us; speedup 1.0000x reference)
//
#include <hip/hip_runtime.h>
#include <hip/hip_bf16.h>

// GraphSAGE 2-layer, bf16 MFMA version.
//   L1: h   = relu([agg1|x] @ [W1l;W1r] + b1)   K=256, N=256, bf16 MFMA
//   L2: [y2|t] = h @ [W2l|W2r] (+b2 on t)       K=256, N=80,  bf16 MFMA
//   out = mean_gather(y2) + t
// R19: k_agg1 restructured node-per-16-lane-segment (4 nodes/wave,
//      16/block). R18 counters: 44.4us, VALU 65%, HBM 33% — per-node
//      fixed cost dominated (mean degree 8 vs 16-edge granularity, 32-op
//      shfl reduce, 1/4-active stores). Now a segment's 16 lanes hold the
//      node's whole row: edge-sum is lane-local (NO cross-lane reduce),
//      stores all-lane coalesced, col load shared by 4 segments, edge
//      granularity 8 (8 loads in flight/instr stream = 32 rows, as R18).
//      Memory transactions unchanged; instruction count per node ~1.5-2x
//      lower. Rest identical to R18 (best: 259.2us).

#define NN   100000
#define NNP  100096          // 782*128 = 1564*64
#define NE   800000
#define NB1  391             // ceil(NN/256)
#define NCHK 32              // edge chunks
#define ECH  25000           // edges per chunk
#define NSLI 16              // node slices
#define NSL  6250            // nodes per slice

typedef unsigned short ushortT;
typedef __attribute__((ext_vector_type(8))) short bf16x8;
typedef __attribute__((ext_vector_type(4))) float f32x4;

__device__ __forceinline__ unsigned short f2b(float f) {
    unsigned u = __float_as_uint(f);
    return (unsigned short)((u + 0x7fffu + ((u >> 16) & 1u)) >> 16);
}
__device__ __forceinline__ float b2f(unsigned short v) {
    return __uint_as_float(((unsigned)v) << 16);
}
__device__ __forceinline__ void llds16(const unsigned short* g, unsigned short* s) {
    __builtin_amdgcn_global_load_lds(
        (const __attribute__((address_space(1))) void*)g,
        (__attribute__((address_space(3))) void*)s, 16, 0, 0);
}
// fragment-major index for weight matrices: value (n,k) lands where the
// MFMA B-operand wants it: chunk=(n>>4)*8+(k>>5), lane=((k>>3)&3)*16+(n&15)
__device__ __forceinline__ int fragIdx(int n, int k) {
    return (((n >> 4) * 8 + (k >> 5)) * 64 + ((k >> 3) & 3) * 16 + (n & 15)) * 8
           + (k & 7);
}

// --------------------------------------------- prep + histogram (pass A)
// blocks [0,12500): x->bf16 cast + weight frag-major transpose/cast
// blocks [12500,13012): block (c,s) LDS-counts chunk-c edges landing in
//                       slice s -> deg32[c][node]; loads 4-batched for MLP
__global__ __launch_bounds__(256) void k_prep(
        const float* __restrict__ x,
        const float* __restrict__ W1l, const float* __restrict__ W1r,
        const float* __restrict__ W2l, const float* __restrict__ W2r,
        ushortT* __restrict__ Ac, ushortT* __restrict__ WT1f,
        ushortT* __restrict__ WT2f,
        const int* __restrict__ dst, int* __restrict__ deg32) {
    __shared__ int hist[NSL];
    int bid = blockIdx.x;
    if (bid < 12500) {
        int t = bid * 256 + threadIdx.x;          // [0, NN*32)
        int row = t >> 5, c4 = t & 31;
        float4 v = *(const float4*)&x[(size_t)row * 128 + c4 * 4];
        ushort4 o;
        o.x = f2b(v.x); o.y = f2b(v.y); o.z = f2b(v.z); o.w = f2b(v.w);
        *(ushort4*)(Ac + (size_t)row * 256 + 128 + c4 * 4) = o;

        if (t < 65536) {                          // WT1f frag-major [256n][256k]
            int n = t >> 8, k = t & 255;
            float w = (k < 128) ? W1l[(size_t)k * 256 + n]
                                : W1r[(size_t)(k - 128) * 256 + n];
            WT1f[fragIdx(n, k)] = f2b(w);
        } else if (t < 65536 + 20480) {           // WT2f frag-major [80n][256k]
            int j = t - 65536;
            int n = j >> 8, k = j & 255;
            float w = (n < 40) ? W2l[(size_t)k * 40 + n]
                               : W2r[(size_t)k * 40 + (n - 40)];
            WT2f[fragIdx(n, k)] = f2b(w);
        }
    } else {
        int idx = bid - 12500;                    // [0,512)
        int s = idx & (NSLI - 1), c = idx >> 4;
        for (int i = threadIdx.x; i < NSL; i += 256) hist[i] = 0;
        __syncthreads();
        int e0 = c * ECH, lo = s * NSL;
        for (int i = threadIdx.x; i < ECH; i += 1024) {
            int d[4];
            bool m[4];
#pragma unroll
            for (int u = 0; u < 4; ++u) {
                int ii = i + u * 256;
                m[u] = ii < ECH;
                d[u] = dst[e0 + (m[u] ? ii : 0)];
            }
#pragma unroll
            for (int u = 0; u < 4; ++u) {
                unsigned dd = (unsigned)(d[u] - lo);
                if (m[u] && dd < (unsigned)NSL) atomicAdd(&hist[dd], 1);
            }
        }
        __syncthreads();
        for (int i = threadIdx.x; i < NSL; i += 256)
            deg32[c * NN + lo + i] = hist[i];
    }
}

// ------------------------------------------- scan over summed chunk degs
__global__ __launch_bounds__(256) void k_scan1(const int* __restrict__ deg32,
                                               int* __restrict__ rp,
                                               int* __restrict__ rpp,
                                               int* __restrict__ bsum) {
    __shared__ int s[256];
    int t = threadIdx.x;
    int i = blockIdx.x * 256 + t;
    int d32[NCHK];
    int v = 0;
#pragma unroll
    for (int r = 0; r < NCHK; ++r) {
        d32[r] = (i < NN) ? deg32[r * NN + i] : 0;
        v += d32[r];
    }
    s[t] = v;
    __syncthreads();
    for (int off = 1; off < 256; off <<= 1) {
        int add = (t >= off) ? s[t - off] : 0;
        __syncthreads();
        s[t] += add;
        __syncthreads();
    }
    int ex = s[t] - v;
    if (i <= NN) rp[i] = ex;                      // i==NN: v=0 -> exclusive end
    if (i < NN) {
        int run = ex;
#pragma unroll
        for (int r = 0; r < NCHK; ++r) {
            rpp[r * NN + i] = run;
            run += d32[r];
        }
    }
    if (t == 255) bsum[blockIdx.x] = s[255];
}

__global__ __launch_bounds__(512) void k_scan2(int* __restrict__ bsum) {
    __shared__ int s[512];
    int t = threadIdx.x;
    int v = (t < NB1) ? bsum[t] : 0;
    s[t] = v;
    __syncthreads();
    for (int off = 1; off < 512; off <<= 1) {
        int add = (t >= off) ? s[t - off] : 0;
        __syncthreads();
        s[t] += add;
        __syncthreads();
    }
    if (t < NB1) bsum[t] = s[t] - v;              // exclusive block offsets
}

// --------------------------------------------------- CSR fill (pass B)
// block (c,s): preload ABSOLUTE offsets off[i]=bsum+rpp (coalesced, LDS),
// then scan chunk c with 4-batched dst/src loads (8 loads in flight before
// any LDS atomic / scatter store).
__global__ __launch_bounds__(256) void k_fillB(const int* __restrict__ src,
                                               const int* __restrict__ dst,
                                               const int* __restrict__ rpp,
                                               const int* __restrict__ bsum,
                                               int* __restrict__ col) {
    __shared__ int off[NSL];
    int s = blockIdx.x & (NSLI - 1), c = blockIdx.x >> 4;
    int lo = s * NSL;
    for (int i = threadIdx.x; i < NSL; i += 256)
        off[i] = bsum[(lo + i) >> 8] + rpp[c * NN + lo + i];
    __syncthreads();
    int e0 = c * ECH;
    for (int i = threadIdx.x; i < ECH; i += 1024) {
        int d[4], sv[4];
        bool m[4];
#pragma unroll
        for (int u = 0; u < 4; ++u) {
            int ii = i + u * 256;
            m[u] = ii < ECH;
            int e = e0 + (m[u] ? ii : 0);
            d[u] = dst[e];
            sv[u] = src[e];
        }
#pragma unroll
        for (int u = 0; u < 4; ++u) {
            unsigned dd = (unsigned)(d[u] - lo);
            if (m[u] && dd < (unsigned)NSL) {
                int k = atomicAdd(&off[dd], 1);   // LDS atomic
                col[k] = sv[u];
            }
        }
    }
}

// ------------------------------------------------------- mean aggregation 1
// gather bf16 x rows (A_cat[:,128:]), write bf16 mean to A_cat[:,0:128].
// R19: one node per 16-lane SEGMENT (4 nodes/wave, 16/block). The segment's
// 16 lanes hold the node's 128-elem row -> edge-sum is lane-local: no
// cross-lane reduce, all-lane coalesced store. Edges 8-at-a-time per
// segment (8 load instrs in flight = 32 rows/wave). col load shared by
// all 4 segments (per-lane beg).
__global__ __launch_bounds__(256) void k_agg1(const int* __restrict__ rp,
                                              const int* __restrict__ bsum,
                                              const int* __restrict__ col,
                                              ushortT* __restrict__ Ac) {
    int l = threadIdx.x & 63;
    int seg = l >> 4, dl = l & 15;
    int node = blockIdx.x * 16 + (threadIdx.x >> 6) * 4 + seg;  // grid exact
    int beg = rp[node] + bsum[node >> 8];
    int deg = rp[node + 1] + bsum[(node + 1) >> 8] - beg;
    float a[8] = {0.f, 0.f, 0.f, 0.f, 0.f, 0.f, 0.f, 0.f};
    for (int base = 0; base < deg; base += 16) {
        int cnt = min(16, deg - base);
        int cv = col[beg + base + min(dl, cnt - 1)];   // 16 edges/segment
        for (int j = 0; j < cnt; j += 8) {
            int idx[8];
            bf16x8 v[8];
#pragma unroll
            for (int u = 0; u < 8; ++u)
                idx[u] = __shfl(cv, seg * 16 + min(j + u, cnt - 1));
#pragma unroll
            for (int u = 0; u < 8; ++u) {
                v[u] = (bf16x8){0, 0, 0, 0, 0, 0, 0, 0};
                if (j + u < cnt)
                    v[u] = *(const bf16x8*)(Ac + (size_t)idx[u] * 256 + 128 + dl * 8);
            }
#pragma unroll
            for (int u = 0; u < 8; ++u)
#pragma unroll
                for (int i = 0; i < 8; ++i)
                    a[i] += b2f((unsigned short)v[u][i]);
        }
    }
    float inv = 1.0f / fmaxf((float)deg, 1.0f);
    bf16x8 o;
#pragma unroll
    for (int i = 0; i < 8; ++i) o[i] = (short)f2b(a[i] * inv);
    *(bf16x8*)(Ac + (size_t)node * 256 + dl * 8) = o;
}

// --------------------------------------------------------- fused L1+L2 GEMM
// Per 64-row block, 8 waves (512 thr):
//   phase1: h64x256 = relu(Ac @ W1^T + b1); wave wid owns 64x32 tile
//           (cols wid*32..wid*32+31), acc 4x2 = 32 AGPR. ALL 16 B-frags
//           (64 VGPR) prefetched before the staging barrier -> their
//           latency overlaps the llds16 drain; K-loop is ds_read+MFMA only.
//   phase2: [y2|t](64x80) = h(LDS) @ W2^T; wave wid<5 owns 16-col tile;
//           its 8 bq frags issued right after phase-1 MFMAs (latency hides
//           under h-park + barrier).
#define HSP 264   // h-tile LDS row stride (+8 pad)
__global__ __launch_bounds__(512, 3) void k_fused(
        const ushortT* __restrict__ Ac, const ushortT* __restrict__ WT1f,
        const float* __restrict__ b1, const ushortT* __restrict__ WT2f,
        const float* __restrict__ b2, ushortT* __restrict__ y2,
        ushortT* __restrict__ t) {
    __shared__ ushortT Bs[64 * HSP];     // 33 KB union buffer
    const int tid = threadIdx.x, l = tid & 63, wid = tid >> 6;
    const int m0 = blockIdx.x * 64;
    const int q = l >> 4, r = l & 15;
    const int swz = (l & 7) ^ ((l >> 3) & 7);

    // ---- stage full A-tile 64x256 as 4 swizzled 64x64 chunks (R11 scheme)
#pragma unroll
    for (int i = 0; i < 4; ++i) {
        int idx = wid * 4 + i;           // 32 issues of 1 KB
        int ktc = idx >> 3, flat = idx & 7;
        int row = flat * 8 + (l >> 3);
        llds16(Ac + (size_t)(m0 + row) * 256 + ktc * 64 + swz * 8,
               &Bs[ktc * 4096 + flat * 512]);
    }

    // ---- prefetch ALL phase-1 B frags: 16 x 1KB coalesced, in flight
    //      across the staging drain.  bfr[kc*2+nt] = B[wid*32+nt*16+r][kc*32+q*8..]
    const ushortT* bBase = WT1f + (size_t)(wid * 16) * 512 + l * 8;
    bf16x8 bfr[16];
#pragma unroll
    for (int kc = 0; kc < 8; ++kc)
#pragma unroll
        for (int nt = 0; nt < 2; ++nt)
            bfr[kc * 2 + nt] = *(const bf16x8*)(bBase + (size_t)(nt * 8 + kc) * 512);

    // bias prefetch (2 floats/lane)
    float bb1[2];
#pragma unroll
    for (int nt = 0; nt < 2; ++nt) bb1[nt] = b1[wid * 32 + nt * 16 + r];

    f32x4 acc[4][2];
#pragma unroll
    for (int i = 0; i < 4; ++i)
#pragma unroll
        for (int j = 0; j < 2; ++j) acc[i][j] = (f32x4){0.f, 0.f, 0.f, 0.f};

    __syncthreads();                     // one drain: staging + all B loads

    // ---- phase 1 K-loop: pure LDS + MFMA (zero global loads)
#pragma unroll
    for (int kc = 0; kc < 8; ++kc) {
        const int ktc = kc >> 1, ks = (kc & 1) * 32;
        const int cs = (((ks >> 3) + q) ^ (r & 7)) * 8;
        bf16x8 af[4];
#pragma unroll
        for (int mt = 0; mt < 4; ++mt)
            af[mt] = *(const bf16x8*)&Bs[ktc * 4096 + (mt * 16 + r) * 64 + cs];
#pragma unroll
        for (int mt = 0; mt < 4; ++mt)
#pragma unroll
            for (int nt = 0; nt < 2; ++nt)
                acc[mt][nt] = __builtin_amdgcn_mfma_f32_16x16x32_bf16(
                    af[mt], bfr[kc * 2 + nt], acc[mt][nt], 0, 0, 0);
    }

    // ---- phase-2 B prefetch: latency hides under park + barrier
    bf16x8 bq[8];
    float bb2 = 0.f;
    if (wid < 5) {
#pragma unroll
        for (int kc = 0; kc < 8; ++kc)
            bq[kc] = *(const bf16x8*)(WT2f + (size_t)(wid * 8 + kc) * 512 + l * 8);
        int c = wid * 16 + r;
        if (c >= 40) bb2 = b2[c - 40];
    }

    __syncthreads();                     // all A reads done; Bs becomes h-tile

    // ---- phase-1 epilogue: +b1, relu, park h-tile in LDS
#pragma unroll
    for (int nt = 0; nt < 2; ++nt) {
        int colb = wid * 32 + nt * 16 + r;
#pragma unroll
        for (int mt = 0; mt < 4; ++mt) {
            int rowb = mt * 16 + q * 4;
#pragma unroll
            for (int j = 0; j < 4; ++j)
                Bs[(rowb + j) * HSP + colb] =
                    f2b(fmaxf(acc[mt][nt][j] + bb1[nt], 0.f));
        }
    }
    __syncthreads();

    // ---- phase 2: [y2|t](64x80) = h(LDS) @ W2^T; wave wid<5 owns 16 cols
    if (wid < 5) {
        f32x4 acc2[4];
#pragma unroll
        for (int j = 0; j < 4; ++j) acc2[j] = (f32x4){0.f, 0.f, 0.f, 0.f};
#pragma unroll
        for (int kc = 0; kc < 8; ++kc) {
            bf16x8 af2[4];
#pragma unroll
            for (int mt = 0; mt < 4; ++mt)
                af2[mt] = *(const bf16x8*)&Bs[(mt * 16 + r) * HSP + kc * 32 + q * 8];
#pragma unroll
            for (int mt = 0; mt < 4; ++mt)
                acc2[mt] = __builtin_amdgcn_mfma_f32_16x16x32_bf16(
                    af2[mt], bq[kc], acc2[mt], 0, 0, 0);
        }
        int c = wid * 16 + r;
#pragma unroll
        for (int mt = 0; mt < 4; ++mt) {
            int row0 = m0 + mt * 16 + q * 4;
#pragma unroll
            for (int j = 0; j < 4; ++j) {
                float v = acc2[mt][j];
                if (c < 40)
                    y2[(size_t)(row0 + j) * 40 + c] = f2b(v);
                else
                    t[(size_t)(row0 + j) * 40 + (c - 40)] = f2b(v + bb2);
            }
        }
    }
}

// ------------------------------------------------------- mean aggregation 2
// out = mean_gather(y2 bf16) + t(bf16); 16 loads in flight.
__global__ __launch_bounds__(256) void k_agg2(const int* __restrict__ rp,
                                              const int* __restrict__ bsum,
                                              const int* __restrict__ col,
                                              const ushortT* __restrict__ y2,
                                              const ushortT* __restrict__ t,
                                              float* __restrict__ out) {
    int node = blockIdx.x * 4 + (threadIdx.x >> 6);
    int l = threadIdx.x & 63;
    if (node >= NN) return;
    int seg = l >> 4, dl = l & 15;
    int beg = rp[node] + bsum[node >> 8];
    int end = rp[node + 1] + bsum[(node + 1) >> 8];
    int deg = end - beg;
    bool act = dl < 10;
    float a0 = 0.f, a1 = 0.f, a2 = 0.f, a3 = 0.f;
    for (int base = 0; base < deg; base += 64) {
        int cnt = min(64, deg - base);
        int cv = col[beg + base + min(l, cnt - 1)];
        for (int j = 0; j < cnt; j += 16) {
            int e[4], idx[4];
            ushort4 v[4];
#pragma unroll
            for (int u = 0; u < 4; ++u) {
                e[u] = j + u * 4 + seg;
                idx[u] = __shfl(cv, min(e[u], cnt - 1));
            }
#pragma unroll
            for (int u = 0; u < 4; ++u) {
                v[u] = (ushort4){0, 0, 0, 0};
                if (e[u] < cnt && act)
                    v[u] = *(const ushort4*)(y2 + (size_t)idx[u] * 40 + dl * 4);
            }
#pragma unroll
            for (int u = 0; u < 4; ++u) {
                a0 += b2f(v[u].x);
                a1 += b2f(v[u].y);
                a2 += b2f(v[u].z);
                a3 += b2f(v[u].w);
            }
        }
    }
    a0 += __shfl_xor(a0, 16); a0 += __shfl_xor(a0, 32);
    a1 += __shfl_xor(a1, 16); a1 += __shfl_xor(a1, 32);
    a2 += __shfl_xor(a2, 16); a2 += __shfl_xor(a2, 32);
    a3 += __shfl_xor(a3, 16); a3 += __shfl_xor(a3, 32);
    if (seg == 0 && act) {
        float inv = 1.0f / fmaxf((float)deg, 1.0f);
        size_t o = (size_t)node * 40 + dl * 4;
        ushort4 tv = *(const ushort4*)&t[o];
        float4 ov;
        ov.x = a0 * inv + b2f(tv.x);
        ov.y = a1 * inv + b2f(tv.y);
        ov.z = a2 * inv + b2f(tv.z);
        ov.w = a3 * inv + b2f(tv.w);
        *(float4*)&out[o] = ov;
    }
}

// ------------------------------------------------------------------- launch
extern "C" void kernel_launch(void* const* d_in, const int* in_sizes, int n_in,
                              void* d_out, int out_size, void* d_ws, size_t ws_size,
                              hipStream_t stream) {
    const float* x   = (const float*)d_in[0];
    const int*   ei  = (const int*)d_in[1];
    const int*   src = ei;
    const int*   dst = ei + NE;
    const float* W1l = (const float*)d_in[2];
    const float* b1  = (const float*)d_in[3];
    const float* W1r = (const float*)d_in[4];
    const float* W2l = (const float*)d_in[5];
    const float* b2  = (const float*)d_in[6];
    const float* W2r = (const float*)d_in[7];
    float* out = (float*)d_out;

    size_t off = 0;
    char* base = (char*)d_ws;
    auto alloc = [&](size_t bytes) -> void* {
        void* p = base + off;
        off += (bytes + 255) & ~(size_t)255;
        return p;
    };
    int*     deg32 = (int*)alloc((size_t)NCHK * NN * 4);
    int*     rp    = (int*)alloc((size_t)(NN + 1) * 4);
    int*     rpp   = (int*)alloc((size_t)NCHK * NN * 4);
    int*     col   = (int*)alloc((size_t)NE * 4);
    int*     bsum  = (int*)alloc(512 * 4);
    ushortT* Ac    = (ushortT*)alloc((size_t)NNP * 256 * 2);   // [agg|x] bf16
    ushortT* y2    = (ushortT*)alloc((size_t)NNP * 40 * 2);
    ushortT* t     = (ushortT*)alloc((size_t)NNP * 40 * 2);
    ushortT* WT1f  = (ushortT*)alloc(256 * 256 * 2);           // frag-major
    ushortT* WT2f  = (ushortT*)alloc(80 * 256 * 2);            // frag-major

    k_prep<<<12500 + NCHK * NSLI, 256, 0, stream>>>(x, W1l, W1r, W2l, W2r,
                                                    Ac, WT1f, WT2f, dst, deg32);
    k_scan1<<<NB1, 256, 0, stream>>>(deg32, rp, rpp, bsum);
    k_scan2<<<1, 512, 0, stream>>>(bsum);
    k_fillB<<<NCHK * NSLI, 256, 0, stream>>>(src, dst, rpp, bsum, col);
    k_agg1<<<NN / 16, 256, 0, stream>>>(rp, bsum, col, Ac);
    k_fused<<<NNP / 64, 512, 0, stream>>>(Ac, WT1f, b1, WT2f, b2, y2, t);
    k_agg2<<<(NN + 3) / 4, 256, 0, stream>>>(rp, bsum, col, y2, t, out);
}

// Round 9
// 245.483 us; speedup vs baseline: 1.0602x; 1.0602x over previous
//
#include <hip/hip_runtime.h>
#include <hip/hip_bf16.h>

// GraphSAGE 2-layer, bf16 MFMA version.
//   L1: h   = relu([agg1|x] @ [W1l;W1r] + b1)   K=256, N=256, bf16 MFMA
//   L2: [y2|t] = h @ [W2l|W2r] (+b2 on t)       K=256, N=80,  bf16 MFMA
//   out = mean_gather(y2) + t
// R20: k_agg2 restructured node-per-16-lane-segment (mirror of R19's
//      agg1 win: 4 nodes/wave, lane-local edge-sum -> no 24-op shfl
//      reduce, store once per wave for 4 nodes, col load shared, edge
//      granularity 8). Gather lane-efficiency unchanged (40/64) so memory
//      traffic identical; removes per-node VALU overhead, which R18->R19
//      showed dominates these gather kernels. Rest identical to R19.

#define NN   100000
#define NNP  100096          // 782*128 = 1564*64
#define NE   800000
#define NB1  391             // ceil(NN/256)
#define NCHK 32              // edge chunks
#define ECH  25000           // edges per chunk
#define NSLI 16              // node slices
#define NSL  6250            // nodes per slice

typedef unsigned short ushortT;
typedef __attribute__((ext_vector_type(8))) short bf16x8;
typedef __attribute__((ext_vector_type(4))) float f32x4;

__device__ __forceinline__ unsigned short f2b(float f) {
    unsigned u = __float_as_uint(f);
    return (unsigned short)((u + 0x7fffu + ((u >> 16) & 1u)) >> 16);
}
__device__ __forceinline__ float b2f(unsigned short v) {
    return __uint_as_float(((unsigned)v) << 16);
}
__device__ __forceinline__ void llds16(const unsigned short* g, unsigned short* s) {
    __builtin_amdgcn_global_load_lds(
        (const __attribute__((address_space(1))) void*)g,
        (__attribute__((address_space(3))) void*)s, 16, 0, 0);
}
// fragment-major index for weight matrices: value (n,k) lands where the
// MFMA B-operand wants it: chunk=(n>>4)*8+(k>>5), lane=((k>>3)&3)*16+(n&15)
__device__ __forceinline__ int fragIdx(int n, int k) {
    return (((n >> 4) * 8 + (k >> 5)) * 64 + ((k >> 3) & 3) * 16 + (n & 15)) * 8
           + (k & 7);
}

// --------------------------------------------- prep + histogram (pass A)
// blocks [0,12500): x->bf16 cast + weight frag-major transpose/cast
// blocks [12500,13012): block (c,s) LDS-counts chunk-c edges landing in
//                       slice s -> deg32[c][node]; loads 4-batched for MLP
__global__ __launch_bounds__(256) void k_prep(
        const float* __restrict__ x,
        const float* __restrict__ W1l, const float* __restrict__ W1r,
        const float* __restrict__ W2l, const float* __restrict__ W2r,
        ushortT* __restrict__ Ac, ushortT* __restrict__ WT1f,
        ushortT* __restrict__ WT2f,
        const int* __restrict__ dst, int* __restrict__ deg32) {
    __shared__ int hist[NSL];
    int bid = blockIdx.x;
    if (bid < 12500) {
        int t = bid * 256 + threadIdx.x;          // [0, NN*32)
        int row = t >> 5, c4 = t & 31;
        float4 v = *(const float4*)&x[(size_t)row * 128 + c4 * 4];
        ushort4 o;
        o.x = f2b(v.x); o.y = f2b(v.y); o.z = f2b(v.z); o.w = f2b(v.w);
        *(ushort4*)(Ac + (size_t)row * 256 + 128 + c4 * 4) = o;

        if (t < 65536) {                          // WT1f frag-major [256n][256k]
            int n = t >> 8, k = t & 255;
            float w = (k < 128) ? W1l[(size_t)k * 256 + n]
                                : W1r[(size_t)(k - 128) * 256 + n];
            WT1f[fragIdx(n, k)] = f2b(w);
        } else if (t < 65536 + 20480) {           // WT2f frag-major [80n][256k]
            int j = t - 65536;
            int n = j >> 8, k = j & 255;
            float w = (n < 40) ? W2l[(size_t)k * 40 + n]
                               : W2r[(size_t)k * 40 + (n - 40)];
            WT2f[fragIdx(n, k)] = f2b(w);
        }
    } else {
        int idx = bid - 12500;                    // [0,512)
        int s = idx & (NSLI - 1), c = idx >> 4;
        for (int i = threadIdx.x; i < NSL; i += 256) hist[i] = 0;
        __syncthreads();
        int e0 = c * ECH, lo = s * NSL;
        for (int i = threadIdx.x; i < ECH; i += 1024) {
            int d[4];
            bool m[4];
#pragma unroll
            for (int u = 0; u < 4; ++u) {
                int ii = i + u * 256;
                m[u] = ii < ECH;
                d[u] = dst[e0 + (m[u] ? ii : 0)];
            }
#pragma unroll
            for (int u = 0; u < 4; ++u) {
                unsigned dd = (unsigned)(d[u] - lo);
                if (m[u] && dd < (unsigned)NSL) atomicAdd(&hist[dd], 1);
            }
        }
        __syncthreads();
        for (int i = threadIdx.x; i < NSL; i += 256)
            deg32[c * NN + lo + i] = hist[i];
    }
}

// ------------------------------------------- scan over summed chunk degs
__global__ __launch_bounds__(256) void k_scan1(const int* __restrict__ deg32,
                                               int* __restrict__ rp,
                                               int* __restrict__ rpp,
                                               int* __restrict__ bsum) {
    __shared__ int s[256];
    int t = threadIdx.x;
    int i = blockIdx.x * 256 + t;
    int d32[NCHK];
    int v = 0;
#pragma unroll
    for (int r = 0; r < NCHK; ++r) {
        d32[r] = (i < NN) ? deg32[r * NN + i] : 0;
        v += d32[r];
    }
    s[t] = v;
    __syncthreads();
    for (int off = 1; off < 256; off <<= 1) {
        int add = (t >= off) ? s[t - off] : 0;
        __syncthreads();
        s[t] += add;
        __syncthreads();
    }
    int ex = s[t] - v;
    if (i <= NN) rp[i] = ex;                      // i==NN: v=0 -> exclusive end
    if (i < NN) {
        int run = ex;
#pragma unroll
        for (int r = 0; r < NCHK; ++r) {
            rpp[r * NN + i] = run;
            run += d32[r];
        }
    }
    if (t == 255) bsum[blockIdx.x] = s[255];
}

__global__ __launch_bounds__(512) void k_scan2(int* __restrict__ bsum) {
    __shared__ int s[512];
    int t = threadIdx.x;
    int v = (t < NB1) ? bsum[t] : 0;
    s[t] = v;
    __syncthreads();
    for (int off = 1; off < 512; off <<= 1) {
        int add = (t >= off) ? s[t - off] : 0;
        __syncthreads();
        s[t] += add;
        __syncthreads();
    }
    if (t < NB1) bsum[t] = s[t] - v;              // exclusive block offsets
}

// --------------------------------------------------- CSR fill (pass B)
// block (c,s): preload ABSOLUTE offsets off[i]=bsum+rpp (coalesced, LDS),
// then scan chunk c with 4-batched dst/src loads (8 loads in flight before
// any LDS atomic / scatter store).
__global__ __launch_bounds__(256) void k_fillB(const int* __restrict__ src,
                                               const int* __restrict__ dst,
                                               const int* __restrict__ rpp,
                                               const int* __restrict__ bsum,
                                               int* __restrict__ col) {
    __shared__ int off[NSL];
    int s = blockIdx.x & (NSLI - 1), c = blockIdx.x >> 4;
    int lo = s * NSL;
    for (int i = threadIdx.x; i < NSL; i += 256)
        off[i] = bsum[(lo + i) >> 8] + rpp[c * NN + lo + i];
    __syncthreads();
    int e0 = c * ECH;
    for (int i = threadIdx.x; i < ECH; i += 1024) {
        int d[4], sv[4];
        bool m[4];
#pragma unroll
        for (int u = 0; u < 4; ++u) {
            int ii = i + u * 256;
            m[u] = ii < ECH;
            int e = e0 + (m[u] ? ii : 0);
            d[u] = dst[e];
            sv[u] = src[e];
        }
#pragma unroll
        for (int u = 0; u < 4; ++u) {
            unsigned dd = (unsigned)(d[u] - lo);
            if (m[u] && dd < (unsigned)NSL) {
                int k = atomicAdd(&off[dd], 1);   // LDS atomic
                col[k] = sv[u];
            }
        }
    }
}

// ------------------------------------------------------- mean aggregation 1
// gather bf16 x rows (A_cat[:,128:]), write bf16 mean to A_cat[:,0:128].
// R19: one node per 16-lane SEGMENT (4 nodes/wave, 16/block). The segment's
// 16 lanes hold the node's 128-elem row -> edge-sum is lane-local: no
// cross-lane reduce, all-lane coalesced store. Edges 8-at-a-time per
// segment (8 load instrs in flight = 32 rows/wave). col load shared by
// all 4 segments (per-lane beg).
__global__ __launch_bounds__(256) void k_agg1(const int* __restrict__ rp,
                                              const int* __restrict__ bsum,
                                              const int* __restrict__ col,
                                              ushortT* __restrict__ Ac) {
    int l = threadIdx.x & 63;
    int seg = l >> 4, dl = l & 15;
    int node = blockIdx.x * 16 + (threadIdx.x >> 6) * 4 + seg;  // grid exact
    int beg = rp[node] + bsum[node >> 8];
    int deg = rp[node + 1] + bsum[(node + 1) >> 8] - beg;
    float a[8] = {0.f, 0.f, 0.f, 0.f, 0.f, 0.f, 0.f, 0.f};
    for (int base = 0; base < deg; base += 16) {
        int cnt = min(16, deg - base);
        int cv = col[beg + base + min(dl, cnt - 1)];   // 16 edges/segment
        for (int j = 0; j < cnt; j += 8) {
            int idx[8];
            bf16x8 v[8];
#pragma unroll
            for (int u = 0; u < 8; ++u)
                idx[u] = __shfl(cv, seg * 16 + min(j + u, cnt - 1));
#pragma unroll
            for (int u = 0; u < 8; ++u) {
                v[u] = (bf16x8){0, 0, 0, 0, 0, 0, 0, 0};
                if (j + u < cnt)
                    v[u] = *(const bf16x8*)(Ac + (size_t)idx[u] * 256 + 128 + dl * 8);
            }
#pragma unroll
            for (int u = 0; u < 8; ++u)
#pragma unroll
                for (int i = 0; i < 8; ++i)
                    a[i] += b2f((unsigned short)v[u][i]);
        }
    }
    float inv = 1.0f / fmaxf((float)deg, 1.0f);
    bf16x8 o;
#pragma unroll
    for (int i = 0; i < 8; ++i) o[i] = (short)f2b(a[i] * inv);
    *(bf16x8*)(Ac + (size_t)node * 256 + dl * 8) = o;
}

// --------------------------------------------------------- fused L1+L2 GEMM
// Per 64-row block, 8 waves (512 thr):
//   phase1: h64x256 = relu(Ac @ W1^T + b1); wave wid owns 64x32 tile
//           (cols wid*32..wid*32+31), acc 4x2 = 32 AGPR. ALL 16 B-frags
//           (64 VGPR) prefetched before the staging barrier -> their
//           latency overlaps the llds16 drain; K-loop is ds_read+MFMA only.
//   phase2: [y2|t](64x80) = h(LDS) @ W2^T; wave wid<5 owns 16-col tile;
//           its 8 bq frags issued right after phase-1 MFMAs (latency hides
//           under h-park + barrier).
#define HSP 264   // h-tile LDS row stride (+8 pad)
__global__ __launch_bounds__(512, 3) void k_fused(
        const ushortT* __restrict__ Ac, const ushortT* __restrict__ WT1f,
        const float* __restrict__ b1, const ushortT* __restrict__ WT2f,
        const float* __restrict__ b2, ushortT* __restrict__ y2,
        ushortT* __restrict__ t) {
    __shared__ ushortT Bs[64 * HSP];     // 33 KB union buffer
    const int tid = threadIdx.x, l = tid & 63, wid = tid >> 6;
    const int m0 = blockIdx.x * 64;
    const int q = l >> 4, r = l & 15;
    const int swz = (l & 7) ^ ((l >> 3) & 7);

    // ---- stage full A-tile 64x256 as 4 swizzled 64x64 chunks (R11 scheme)
#pragma unroll
    for (int i = 0; i < 4; ++i) {
        int idx = wid * 4 + i;           // 32 issues of 1 KB
        int ktc = idx >> 3, flat = idx & 7;
        int row = flat * 8 + (l >> 3);
        llds16(Ac + (size_t)(m0 + row) * 256 + ktc * 64 + swz * 8,
               &Bs[ktc * 4096 + flat * 512]);
    }

    // ---- prefetch ALL phase-1 B frags: 16 x 1KB coalesced, in flight
    //      across the staging drain.  bfr[kc*2+nt] = B[wid*32+nt*16+r][kc*32+q*8..]
    const ushortT* bBase = WT1f + (size_t)(wid * 16) * 512 + l * 8;
    bf16x8 bfr[16];
#pragma unroll
    for (int kc = 0; kc < 8; ++kc)
#pragma unroll
        for (int nt = 0; nt < 2; ++nt)
            bfr[kc * 2 + nt] = *(const bf16x8*)(bBase + (size_t)(nt * 8 + kc) * 512);

    // bias prefetch (2 floats/lane)
    float bb1[2];
#pragma unroll
    for (int nt = 0; nt < 2; ++nt) bb1[nt] = b1[wid * 32 + nt * 16 + r];

    f32x4 acc[4][2];
#pragma unroll
    for (int i = 0; i < 4; ++i)
#pragma unroll
        for (int j = 0; j < 2; ++j) acc[i][j] = (f32x4){0.f, 0.f, 0.f, 0.f};

    __syncthreads();                     // one drain: staging + all B loads

    // ---- phase 1 K-loop: pure LDS + MFMA (zero global loads)
#pragma unroll
    for (int kc = 0; kc < 8; ++kc) {
        const int ktc = kc >> 1, ks = (kc & 1) * 32;
        const int cs = (((ks >> 3) + q) ^ (r & 7)) * 8;
        bf16x8 af[4];
#pragma unroll
        for (int mt = 0; mt < 4; ++mt)
            af[mt] = *(const bf16x8*)&Bs[ktc * 4096 + (mt * 16 + r) * 64 + cs];
#pragma unroll
        for (int mt = 0; mt < 4; ++mt)
#pragma unroll
            for (int nt = 0; nt < 2; ++nt)
                acc[mt][nt] = __builtin_amdgcn_mfma_f32_16x16x32_bf16(
                    af[mt], bfr[kc * 2 + nt], acc[mt][nt], 0, 0, 0);
    }

    // ---- phase-2 B prefetch: latency hides under park + barrier
    bf16x8 bq[8];
    float bb2 = 0.f;
    if (wid < 5) {
#pragma unroll
        for (int kc = 0; kc < 8; ++kc)
            bq[kc] = *(const bf16x8*)(WT2f + (size_t)(wid * 8 + kc) * 512 + l * 8);
        int c = wid * 16 + r;
        if (c >= 40) bb2 = b2[c - 40];
    }

    __syncthreads();                     // all A reads done; Bs becomes h-tile

    // ---- phase-1 epilogue: +b1, relu, park h-tile in LDS
#pragma unroll
    for (int nt = 0; nt < 2; ++nt) {
        int colb = wid * 32 + nt * 16 + r;
#pragma unroll
        for (int mt = 0; mt < 4; ++mt) {
            int rowb = mt * 16 + q * 4;
#pragma unroll
            for (int j = 0; j < 4; ++j)
                Bs[(rowb + j) * HSP + colb] =
                    f2b(fmaxf(acc[mt][nt][j] + bb1[nt], 0.f));
        }
    }
    __syncthreads();

    // ---- phase 2: [y2|t](64x80) = h(LDS) @ W2^T; wave wid<5 owns 16 cols
    if (wid < 5) {
        f32x4 acc2[4];
#pragma unroll
        for (int j = 0; j < 4; ++j) acc2[j] = (f32x4){0.f, 0.f, 0.f, 0.f};
#pragma unroll
        for (int kc = 0; kc < 8; ++kc) {
            bf16x8 af2[4];
#pragma unroll
            for (int mt = 0; mt < 4; ++mt)
                af2[mt] = *(const bf16x8*)&Bs[(mt * 16 + r) * HSP + kc * 32 + q * 8];
#pragma unroll
            for (int mt = 0; mt < 4; ++mt)
                acc2[mt] = __builtin_amdgcn_mfma_f32_16x16x32_bf16(
                    af2[mt], bq[kc], acc2[mt], 0, 0, 0);
        }
        int c = wid * 16 + r;
#pragma unroll
        for (int mt = 0; mt < 4; ++mt) {
            int row0 = m0 + mt * 16 + q * 4;
#pragma unroll
            for (int j = 0; j < 4; ++j) {
                float v = acc2[mt][j];
                if (c < 40)
                    y2[(size_t)(row0 + j) * 40 + c] = f2b(v);
                else
                    t[(size_t)(row0 + j) * 40 + (c - 40)] = f2b(v + bb2);
            }
        }
    }
}

// ------------------------------------------------------- mean aggregation 2
// out = mean_gather(y2 bf16) + t(bf16).
// R20: one node per 16-lane SEGMENT (4 nodes/wave, 16/block); lanes dl<10
// hold the node's 40-col row as ushort4 -> edge-sum lane-local (no shfl
// reduce), store once per wave for 4 nodes, col load shared, edges
// 8-at-a-time (8 load instrs in flight).
__global__ __launch_bounds__(256) void k_agg2(const int* __restrict__ rp,
                                              const int* __restrict__ bsum,
                                              const int* __restrict__ col,
                                              const ushortT* __restrict__ y2,
                                              const ushortT* __restrict__ t,
                                              float* __restrict__ out) {
    int l = threadIdx.x & 63;
    int seg = l >> 4, dl = l & 15;
    int node = blockIdx.x * 16 + (threadIdx.x >> 6) * 4 + seg;  // grid exact
    int beg = rp[node] + bsum[node >> 8];
    int deg = rp[node + 1] + bsum[(node + 1) >> 8] - beg;
    bool act = dl < 10;
    float a0 = 0.f, a1 = 0.f, a2 = 0.f, a3 = 0.f;
    for (int base = 0; base < deg; base += 16) {
        int cnt = min(16, deg - base);
        int cv = col[beg + base + min(dl, cnt - 1)];   // 16 edges/segment
        for (int j = 0; j < cnt; j += 8) {
            int idx[8];
            ushort4 v[8];
#pragma unroll
            for (int u = 0; u < 8; ++u)
                idx[u] = __shfl(cv, seg * 16 + min(j + u, cnt - 1));
#pragma unroll
            for (int u = 0; u < 8; ++u) {
                v[u] = (ushort4){0, 0, 0, 0};
                if (j + u < cnt && act)
                    v[u] = *(const ushort4*)(y2 + (size_t)idx[u] * 40 + dl * 4);
            }
#pragma unroll
            for (int u = 0; u < 8; ++u) {
                a0 += b2f(v[u].x);
                a1 += b2f(v[u].y);
                a2 += b2f(v[u].z);
                a3 += b2f(v[u].w);
            }
        }
    }
    if (act) {
        float inv = 1.0f / fmaxf((float)deg, 1.0f);
        size_t o = (size_t)node * 40 + dl * 4;
        ushort4 tv = *(const ushort4*)&t[o];
        float4 ov;
        ov.x = a0 * inv + b2f(tv.x);
        ov.y = a1 * inv + b2f(tv.y);
        ov.z = a2 * inv + b2f(tv.z);
        ov.w = a3 * inv + b2f(tv.w);
        *(float4*)&out[o] = ov;
    }
}

// ------------------------------------------------------------------- launch
extern "C" void kernel_launch(void* const* d_in, const int* in_sizes, int n_in,
                              void* d_out, int out_size, void* d_ws, size_t ws_size,
                              hipStream_t stream) {
    const float* x   = (const float*)d_in[0];
    const int*   ei  = (const int*)d_in[1];
    const int*   src = ei;
    const int*   dst = ei + NE;
    const float* W1l = (const float*)d_in[2];
    const float* b1  = (const float*)d_in[3];
    const float* W1r = (const float*)d_in[4];
    const float* W2l = (const float*)d_in[5];
    const float* b2  = (const float*)d_in[6];
    const float* W2r = (const float*)d_in[7];
    float* out = (float*)d_out;

    size_t off = 0;
    char* base = (char*)d_ws;
    auto alloc = [&](size_t bytes) -> void* {
        void* p = base + off;
        off += (bytes + 255) & ~(size_t)255;
        return p;
    };
    int*     deg32 = (int*)alloc((size_t)NCHK * NN * 4);
    int*     rp    = (int*)alloc((size_t)(NN + 1) * 4);
    int*     rpp   = (int*)alloc((size_t)NCHK * NN * 4);
    int*     col   = (int*)alloc((size_t)NE * 4);
    int*     bsum  = (int*)alloc(512 * 4);
    ushortT* Ac    = (ushortT*)alloc((size_t)NNP * 256 * 2);   // [agg|x] bf16
    ushortT* y2    = (ushortT*)alloc((size_t)NNP * 40 * 2);
    ushortT* t     = (ushortT*)alloc((size_t)NNP * 40 * 2);
    ushortT* WT1f  = (ushortT*)alloc(256 * 256 * 2);           // frag-major
    ushortT* WT2f  = (ushortT*)alloc(80 * 256 * 2);            // frag-major

    k_prep<<<12500 + NCHK * NSLI, 256, 0, stream>>>(x, W1l, W1r, W2l, W2r,
                                                    Ac, WT1f, WT2f, dst, deg32);
    k_scan1<<<NB1, 256, 0, stream>>>(deg32, rp, rpp, bsum);
    k_scan2<<<1, 512, 0, stream>>>(bsum);
    k_fillB<<<NCHK * NSLI, 256, 0, stream>>>(src, dst, rpp, bsum, col);
    k_agg1<<<NN / 16, 256, 0, stream>>>(rp, bsum, col, Ac);
    k_fused<<<NNP / 64, 512, 0, stream>>>(Ac, WT1f, b1, WT2f, b2, y2, t);
    k_agg2<<<NN / 16, 256, 0, stream>>>(rp, bsum, col, y2, t, out);
}